// Round 1
// baseline (245.074 us; speedup 1.0000x reference)
//
#include <hip/hip_runtime.h>

// out[i] = g(data[i]) where g = (x*MAXVAL*ct) -> 3 Hermite-spline ODE steps -> (*st/MAXVAL).
// g is piecewise-smooth on [0,4] (post-ct space) and exactly affine outside.
// Pre-kernel tabulates g (value-only) at 512 knots over [-0.5, 4.5] into d_ws.
//
// R4: latency/occupancy attack. R3 was ~80us with every pipe <20% busy and
// OccupancyPercent=33 (self-capped at 62.5% by 32KiB LDS). Changes:
//  - REP 16 -> 8: LDS 32KiB -> 16KiB => occupancy cap 20 -> 32 waves/CU,
//    fill cost halved. Bank spread still ~2-way avg (free, m136); conflicts
//    were proven non-binding (R0/R2/R3 all ~80us across conflict counts).
//  - Persistent-ish grid: 2048 blocks x 4 chunks (exact cover of 8,388,608
//    float4) => per-block table fill amortized 4x (total fill work / 4).
//  - Cross-chunk double-buffer: chunk c+1's 4 float4 loads are issued before
//    the lerp+store of chunk c, keeping HBM loads in flight during the
//    dependent LDS/VALU phase (the phase that previously had zero MLP).
//  - __launch_bounds__(256, 8) pins VGPR <= 64 so 8 blocks/CU actually fit.

#define MAXVAL_F 1.1752011936438014f

typedef float nfloat4 __attribute__((ext_vector_type(4)));  // native vec for nt-store

constexpr int   TAB_K  = 512;                    // knots
constexpr int   REP    = 8;                      // lane replicas (lane & 7)
constexpr float TAB_L0 = -0.5f;
constexpr float TAB_HI = 4.5f;
constexpr float INV_H  = (float)(TAB_K - 1) / (TAB_HI - TAB_L0);  // 511/5
constexpr int   ITER   = 4;                      // float4 per thread per chunk
constexpr int   BLK    = 256;
constexpr int   NCHUNK = 4;                      // chunks per block (fill amortization)
constexpr int   F4_PER_CHUNK = BLK * ITER;       // 1024
constexpr int   F4_PER_BLOCK = F4_PER_CHUNK * NCHUNK;  // 4096 -> 2048 blocks exactly

// Exact reference-faithful evaluation of the 3-step map in post-ct space
// (excluding the final st/MAXVAL scale).
__device__ __forceinline__ float eval_exact(float x,
    const float* __restrict__ vt, const float* __restrict__ at) {
#pragma unroll
  for (int k = 0; k < 3; ++k) {
    float t = fminf(fmaxf(x, 0.0f), 4.0f);   // clip(x, 0, NUM_POINTS-1)
    int i0 = (int)t;                          // t >= 0 so trunc == floor
    if (i0 > 3) i0 = 3;                       // clip to NUM_POINTS-2
    float u  = t - (float)i0;
    float u2 = u * u, u3 = u2 * u;
    float h00 =  2.0f * u3 - 3.0f * u2 + 1.0f;
    float h10 =         u3 - 2.0f * u2 + u;
    float h01 = -2.0f * u3 + 3.0f * u2;
    float h11 =         u3 -        u2;
    // table layout: row 0 = values [0..4], row 1 = tangents [5..9]
    float vel = h00 * vt[i0] + h10 * vt[5 + i0] + h01 * vt[i0 + 1] + h11 * vt[6 + i0];
    float ang = h00 * at[i0] + h10 * at[5 + i0] + h01 * at[i0 + 1] + h11 * at[6 + i0];
    float sn = sinf(ang);
    float cs = cosf(ang);
    x = x + (vel * cs + x * vel * sn) * (1.0f / 3.0f);
  }
  return x;
}

// Tiny launch: knot values of the composed map, fully scaled.
__global__ void build_table_kernel(const float* __restrict__ vt,
                                   const float* __restrict__ at,
                                   const float* __restrict__ stp,
                                   float* __restrict__ gtab) {
  int j = blockIdx.x * blockDim.x + threadIdx.x;
  if (j >= TAB_K) return;
  float sc = stp[0] * (1.0f / MAXVAL_F);
  float x  = TAB_L0 + (float)j / INV_H;
  gtab[j] = eval_exact(x, vt, at) * sc;
}

__device__ __forceinline__ void nt_store4(float4 o, float4* p) {
  nfloat4 v = {o.x, o.y, o.z, o.w};
  __builtin_nontemporal_store(v, (nfloat4*)p);
}

// Per-element lerp from the bank-private replicated table.
// Index clamp WITHOUT clamping u -> linear extrapolation, exact in the affine tails.
__device__ __forceinline__ float lerp_tab(float x, float C1, float C0, int lrep,
                                          const float* __restrict__ vrep) {
  float s  = fmaf(x, C1, C0);
  float fj = fminf(fmaxf(floorf(s), 0.0f), (float)(TAB_K - 2));
  float u  = s - fj;                       // may be <0 or >1: extrapolation
  int   off = ((int)fj << 3) | lrep;       // replica l&7
  float a0 = vrep[off];
  float a1 = vrep[off + REP];              // +32B: fuses to ds_read2_b32
  return fmaf(u, a1 - a0, a0);
}

// Lerp + nt-store one chunk held in registers.
__device__ __forceinline__ void proc_store(const float4* d, int cbase,
    float4* __restrict__ out, float C1, float C0, int lrep,
    const float* __restrict__ vrep) {
#pragma unroll
  for (int j = 0; j < ITER; ++j) {
    float4 o;
    o.x = lerp_tab(d[j].x, C1, C0, lrep, vrep);
    o.y = lerp_tab(d[j].y, C1, C0, lrep, vrep);
    o.z = lerp_tab(d[j].z, C1, C0, lrep, vrep);
    o.w = lerp_tab(d[j].w, C1, C0, lrep, vrep);
    nt_store4(o, &out[cbase + j * BLK]);
  }
}

__global__ __launch_bounds__(BLK, 8) void apply_map_kernel(
    const float4* __restrict__ in, float4* __restrict__ out,
    const float* __restrict__ gtab, const float* __restrict__ ctp, int nf4) {
  __shared__ float vrep[TAB_K * REP];      // 512*8*4 = 16 KiB -> 8 blocks/CU
  {
    // addr = tid + k*256 -> bank = tid%32: conflict-free writes.
    // gather loads hit L2 (gtab is 2 KiB, hot after block 0).
#pragma unroll
    for (int k = 0; k < (TAB_K * REP) / BLK; ++k) {   // 16 iterations
      int i = (int)threadIdx.x + k * BLK;
      vrep[i] = gtab[i >> 3];
    }
  }
  float C1 = ctp[0] * (MAXVAL_F * INV_H);  // s = data*C1 + C0
  const float C0 = -TAB_L0 * INV_H;
  int lrep = (int)threadIdx.x & (REP - 1);

  int base = (int)blockIdx.x * F4_PER_BLOCK + (int)threadIdx.x;

  if ((int)blockIdx.x * F4_PER_BLOCK + F4_PER_BLOCK <= nf4) {
    // Fast path (always taken at N=2^25: 2048 blocks * 4096 f4 exact).
    // Software pipeline: loads of chunk c+1 in flight while chunk c lerps+stores.
    float4 dA[ITER], dB[ITER];
#pragma unroll
    for (int j = 0; j < ITER; ++j) dA[j] = in[base + j * BLK];          // chunk 0
    __syncthreads();
#pragma unroll
    for (int j = 0; j < ITER; ++j) dB[j] = in[base + F4_PER_CHUNK + j * BLK];      // chunk 1
    proc_store(dA, base, out, C1, C0, lrep, vrep);                                  // chunk 0
#pragma unroll
    for (int j = 0; j < ITER; ++j) dA[j] = in[base + 2 * F4_PER_CHUNK + j * BLK];  // chunk 2
    proc_store(dB, base + F4_PER_CHUNK, out, C1, C0, lrep, vrep);                   // chunk 1
#pragma unroll
    for (int j = 0; j < ITER; ++j) dB[j] = in[base + 3 * F4_PER_CHUNK + j * BLK];  // chunk 3
    proc_store(dA, base + 2 * F4_PER_CHUNK, out, C1, C0, lrep, vrep);               // chunk 2
    proc_store(dB, base + 3 * F4_PER_CHUNK, out, C1, C0, lrep, vrep);               // chunk 3
  } else {                                  // ragged tail (unused at N=2^25)
    __syncthreads();
#pragma unroll
    for (int c = 0; c < NCHUNK; ++c) {
#pragma unroll
      for (int j = 0; j < ITER; ++j) {
        int idx = base + c * F4_PER_CHUNK + j * BLK;
        if (idx < nf4) {
          float4 d = in[idx];
          float4 o;
          o.x = lerp_tab(d.x, C1, C0, lrep, vrep);
          o.y = lerp_tab(d.y, C1, C0, lrep, vrep);
          o.z = lerp_tab(d.z, C1, C0, lrep, vrep);
          o.w = lerp_tab(d.w, C1, C0, lrep, vrep);
          nt_store4(o, &out[idx]);
        }
      }
    }
  }
}

extern "C" void kernel_launch(void* const* d_in, const int* in_sizes, int n_in,
                              void* d_out, int out_size, void* d_ws, size_t ws_size,
                              hipStream_t stream) {
  const float* data = (const float*)d_in[0];
  const float* vel  = (const float*)d_in[1];
  const float* ang  = (const float*)d_in[2];
  const float* ct   = (const float*)d_in[3];
  const float* st   = (const float*)d_in[4];
  float*       outp = (float*)d_out;
  float*       gtab = (float*)d_ws;   // 512 * 4 B = 2 KiB scratch

  hipLaunchKernelGGL(build_table_kernel, dim3((TAB_K + 255) / 256), dim3(256), 0, stream,
                     vel, ang, st, gtab);

  int n   = in_sizes[0];          // 33,554,432
  int nf4 = n / 4;                // 8,388,608 = 2048 * 4096 exactly
  int blocks = (nf4 + F4_PER_BLOCK - 1) / F4_PER_BLOCK;   // 2048 -> 8 blocks/CU
  hipLaunchKernelGGL(apply_map_kernel, dim3(blocks), dim3(BLK), 0, stream,
                     (const float4*)data, (float4*)outp, gtab, ct, nf4);
}